// Round 3
// baseline (3308.079 us; speedup 1.0000x reference)
//
#include <hip/hip_runtime.h>
#include <hip/hip_bf16.h>

#define SEQ 512
#define BATCH 64
#define IN 256
#define HID 512
#define NG 1536  // 3*HID

typedef short short8 __attribute__((ext_vector_type(8)));
typedef float f32x4 __attribute__((ext_vector_type(4)));

__device__ __forceinline__ unsigned short f2bf(float f) {
    union { float f; unsigned u; } v; v.f = f;
    return (unsigned short)((v.u + 0x7fffu + ((v.u >> 16) & 1u)) >> 16);
}
__device__ __forceinline__ float bf2f(unsigned short h) {
    union { unsigned u; float f; } v; v.u = ((unsigned)h) << 16; return v.f;
}

// Build gate-major bf16 weight blocks + folded bias constants.
__global__ void prep_weights(const float* __restrict__ Wr, const float* __restrict__ br,
                             const float* __restrict__ Wu, const float* __restrict__ bu,
                             const float* __restrict__ Wni, const float* __restrict__ bni,
                             const float* __restrict__ Wnh, const float* __restrict__ bnh,
                             unsigned short* __restrict__ WxT, unsigned short* __restrict__ WhT,
                             float* __restrict__ biases)
{
    int n = blockIdx.x * blockDim.x + threadIdx.x;
    if (n >= NG) return;
    int g = n >> 9, j = n & 511;
    const float* xsrc; const float* hsrc; float bias;
    if (g == 0)      { xsrc = Wr + (size_t)j*770; hsrc = Wr + (size_t)j*770 + 257;
                       bias = Wr[(size_t)j*770+256] + Wr[(size_t)j*770+769] + br[j]; }
    else if (g == 1) { xsrc = Wu + (size_t)j*770; hsrc = Wu + (size_t)j*770 + 257;
                       bias = Wu[(size_t)j*770+256] + Wu[(size_t)j*770+769] + bu[j]; }
    else             { xsrc = Wni + (size_t)j*257; hsrc = Wnh + (size_t)j*513;
                       bias = Wni[(size_t)j*257+256] + bni[j]; }
    for (int i = 0; i < IN; ++i)  WxT[(size_t)n*IN + i]  = f2bf(xsrc[i]);
    for (int k = 0; k < HID; ++k) WhT[(size_t)n*HID + k] = f2bf(hsrc[k]);
    biases[n] = bias;
    if (g == 2) biases[NG + j] = Wnh[(size_t)j*513 + 512] + bnh[j];
}

__global__ void cvt_x(const float* __restrict__ x, unsigned short* __restrict__ xb, int n)
{
    int i = (blockIdx.x * blockDim.x + threadIdx.x) * 4;
    if (i >= n) return;
    float4 v = *reinterpret_cast<const float4*>(x + i);
    ushort4 o;
    o.x = f2bf(v.x); o.y = f2bf(v.y); o.z = f2bf(v.z); o.w = f2bf(v.w);
    *reinterpret_cast<ushort4*>(xb + i) = o;
}

// Gx[m][n] = sum_i xb[m][i]*WxT[n][i] + biases[n],  m = t*64+b, stored bf16.
__global__ __launch_bounds__(256) void gemm_x(const unsigned short* __restrict__ xb,
                                              const unsigned short* __restrict__ WxT,
                                              const float* __restrict__ biases,
                                              unsigned short* __restrict__ Gx)
{
    const int lane = threadIdx.x & 63;
    const int wave = threadIdx.x >> 6;
    const int m0 = blockIdx.x * 64;
    const int n0 = blockIdx.y * 256 + wave * 64;
    const int laneM = lane & 15, laneK8 = (lane >> 4) * 8;
    f32x4 acc[4][4] = {};
#pragma unroll
    for (int k0 = 0; k0 < IN; k0 += 32) {
        short8 A[4], Bf[4];
#pragma unroll
        for (int mi = 0; mi < 4; ++mi)
            A[mi] = *reinterpret_cast<const short8*>(xb + (size_t)(m0 + mi*16 + laneM)*IN + k0 + laneK8);
#pragma unroll
        for (int ni = 0; ni < 4; ++ni)
            Bf[ni] = *reinterpret_cast<const short8*>(WxT + (size_t)(n0 + ni*16 + laneM)*IN + k0 + laneK8);
#pragma unroll
        for (int mi = 0; mi < 4; ++mi)
#pragma unroll
            for (int ni = 0; ni < 4; ++ni)
                acc[mi][ni] = __builtin_amdgcn_mfma_f32_16x16x32_bf16(A[mi], Bf[ni], acc[mi][ni], 0, 0, 0);
    }
    const int crow = (lane >> 4) * 4, ccol = lane & 15;
#pragma unroll
    for (int mi = 0; mi < 4; ++mi)
#pragma unroll
        for (int ni = 0; ni < 4; ++ni) {
            int nn = n0 + ni*16 + ccol;
            float bias = biases[nn];
#pragma unroll
            for (int v = 0; v < 4; ++v) {
                int mm = m0 + mi*16 + crow + v;
                Gx[(size_t)mm * NG + nn] = f2bf(acc[mi][ni][v] + bias);
            }
        }
}

// Persistent recurrent kernel. 128 blocks x 256 threads (cooperative launch).
// 4 independent batch groups (mt) of 32 blocks. Synchronization is embedded in
// the data: h is stored as u32 = (tag<<16)|bf16, tag = step index of the h value.
// Consumers poll-load their MFMA A-fragments until every word's tag == t; at
// that point operands are already in registers. No fences, no flags, no drains.
__global__ __launch_bounds__(256) void gru_seq(const unsigned short* __restrict__ Gx,
                                               const unsigned short* __restrict__ WhT,
                                               const float* __restrict__ biases,
                                               unsigned* __restrict__ htag,
                                               float* __restrict__ out)
{
    const int blk = blockIdx.x;
    const int mt = blk >> 5, jt = blk & 31;
    const int m0 = mt * 16, j0 = jt * 16;
    const int lane = threadIdx.x & 63;
    const int wave = threadIdx.x >> 6;
    const int laneM = lane & 15, laneK8 = (lane >> 4) * 8;
    __shared__ float red[4][3][16][16];

    // Preload recurrent weight fragments once (invariant over t).
    short8 Bf[3][4];
#pragma unroll
    for (int g = 0; g < 3; ++g)
#pragma unroll
        for (int kk = 0; kk < 4; ++kk) {
            int n = g * HID + j0 + laneM;
            int k = wave * 128 + kk * 32 + laneK8;
            Bf[g][kk] = *reinterpret_cast<const short8*>(WhT + (size_t)n * HID + k);
        }

    const int row = threadIdx.x >> 4, col = threadIdx.x & 15;
    const int b = m0 + row, j = j0 + col;
    const float cnh = biases[NG + j];
    float h_old = 0.f;
    const size_t gx0 = (size_t)b * NG + j;
    unsigned short pr = Gx[gx0], pu = Gx[gx0 + HID], pn = Gx[gx0 + 2*HID];

    // Per-thread base of the tagged-h row this wave reads (A-fragment source).
    const unsigned* hrow = htag + (size_t)(m0 + laneM) * HID + wave * 128 + laneK8;

    for (int t = 0; t < SEQ; ++t) {
        // Prefetch next step's x-projections (normal cached loads, independent).
        unsigned short nr = 0, nu = 0, nn2 = 0;
        if (t + 1 < SEQ) {
            size_t gi = gx0 + (size_t)(t + 1) * BATCH * NG;
            nr = Gx[gi]; nu = Gx[gi + HID]; nn2 = Gx[gi + 2*HID];
        }

        // Poll-load tagged h_t words until all fresh (tag == t).
        const unsigned* hp = hrow + (size_t)(t & 1) * BATCH * HID;
        const unsigned need = (unsigned)t << 16;
        unsigned u0[8], u1[8], u2[8], u3[8];
        for (;;) {
            unsigned bad = 0;
#pragma unroll
            for (int w = 0; w < 8; ++w)
                u0[w] = __hip_atomic_load(hp +  0 + w, __ATOMIC_RELAXED, __HIP_MEMORY_SCOPE_AGENT);
#pragma unroll
            for (int w = 0; w < 8; ++w)
                u1[w] = __hip_atomic_load(hp + 32 + w, __ATOMIC_RELAXED, __HIP_MEMORY_SCOPE_AGENT);
#pragma unroll
            for (int w = 0; w < 8; ++w)
                u2[w] = __hip_atomic_load(hp + 64 + w, __ATOMIC_RELAXED, __HIP_MEMORY_SCOPE_AGENT);
#pragma unroll
            for (int w = 0; w < 8; ++w)
                u3[w] = __hip_atomic_load(hp + 96 + w, __ATOMIC_RELAXED, __HIP_MEMORY_SCOPE_AGENT);
#pragma unroll
            for (int w = 0; w < 8; ++w)
                bad |= ((u0[w] ^ need) | (u1[w] ^ need) | (u2[w] ^ need) | (u3[w] ^ need)) & 0xffff0000u;
            if (__all(bad == 0)) break;
        }
        // Pack bf16 payloads into MFMA A fragments.
        union { unsigned p[4]; short8 s; } pk;
        short8 A[4];
        pk.p[0] = (u0[0] & 0xffffu) | (u0[1] << 16); pk.p[1] = (u0[2] & 0xffffu) | (u0[3] << 16);
        pk.p[2] = (u0[4] & 0xffffu) | (u0[5] << 16); pk.p[3] = (u0[6] & 0xffffu) | (u0[7] << 16);
        A[0] = pk.s;
        pk.p[0] = (u1[0] & 0xffffu) | (u1[1] << 16); pk.p[1] = (u1[2] & 0xffffu) | (u1[3] << 16);
        pk.p[2] = (u1[4] & 0xffffu) | (u1[5] << 16); pk.p[3] = (u1[6] & 0xffffu) | (u1[7] << 16);
        A[1] = pk.s;
        pk.p[0] = (u2[0] & 0xffffu) | (u2[1] << 16); pk.p[1] = (u2[2] & 0xffffu) | (u2[3] << 16);
        pk.p[2] = (u2[4] & 0xffffu) | (u2[5] << 16); pk.p[3] = (u2[6] & 0xffffu) | (u2[7] << 16);
        A[2] = pk.s;
        pk.p[0] = (u3[0] & 0xffffu) | (u3[1] << 16); pk.p[1] = (u3[2] & 0xffffu) | (u3[3] << 16);
        pk.p[2] = (u3[4] & 0xffffu) | (u3[5] << 16); pk.p[3] = (u3[6] & 0xffffu) | (u3[7] << 16);
        A[3] = pk.s;

        f32x4 aR = {0,0,0,0}, aU = {0,0,0,0}, aN = {0,0,0,0};
#pragma unroll
        for (int kk = 0; kk < 4; ++kk) {
            aR = __builtin_amdgcn_mfma_f32_16x16x32_bf16(A[kk], Bf[0][kk], aR, 0, 0, 0);
            aU = __builtin_amdgcn_mfma_f32_16x16x32_bf16(A[kk], Bf[1][kk], aU, 0, 0, 0);
            aN = __builtin_amdgcn_mfma_f32_16x16x32_bf16(A[kk], Bf[2][kk], aN, 0, 0, 0);
        }
        const int crow = (lane >> 4) * 4;
#pragma unroll
        for (int v = 0; v < 4; ++v) {
            red[wave][0][crow + v][laneM] = aR[v];
            red[wave][1][crow + v][laneM] = aU[v];
            red[wave][2][crow + v][laneM] = aN[v];
        }
        __syncthreads();
        float rp = red[0][0][row][col] + red[1][0][row][col] + red[2][0][row][col] + red[3][0][row][col];
        float up = red[0][1][row][col] + red[1][1][row][col] + red[2][1][row][col] + red[3][1][row][col];
        float np = red[0][2][row][col] + red[1][2][row][col] + red[2][2][row][col] + red[3][2][row][col];
        float r = 1.f / (1.f + __expf(-(bf2f(pr) + rp)));
        float z = 1.f / (1.f + __expf(-(bf2f(pu) + up)));
        float e = __expf(2.f * (bf2f(pn) + r * (np + cnh)));
        float n = 1.f - 2.f / (e + 1.f);
        float hnew = (1.f - z) * n + z * h_old;
        h_old = hnew;

        // Publish tagged h_{t+1} word — fire and forget, no drain needed.
        __hip_atomic_store(htag + (size_t)((t + 1) & 1) * BATCH * HID + (size_t)b * HID + j,
                           ((unsigned)(t + 1) << 16) | (unsigned)f2bf(hnew),
                           __ATOMIC_RELAXED, __HIP_MEMORY_SCOPE_AGENT);

        out[(size_t)t * BATCH * HID + (size_t)b * HID + j] = hnew;
        if (t == SEQ - 1) out[(size_t)SEQ * BATCH * HID + (size_t)b * HID + j] = hnew;
        pr = nr; pu = nu; pn = nn2;

        __syncthreads();  // WAR protection for red[] before next iteration
    }
}

extern "C" void kernel_launch(void* const* d_in, const int* in_sizes, int n_in,
                              void* d_out, int out_size, void* d_ws, size_t ws_size,
                              hipStream_t stream)
{
    const float* x   = (const float*)d_in[0];
    const float* Wr  = (const float*)d_in[1];
    const float* br  = (const float*)d_in[2];
    const float* Wu  = (const float*)d_in[3];
    const float* bu  = (const float*)d_in[4];
    const float* Wni = (const float*)d_in[5];
    const float* bni = (const float*)d_in[6];
    const float* Wnh = (const float*)d_in[7];
    const float* bnh = (const float*)d_in[8];
    float* out = (float*)d_out;

    char* ws = (char*)d_ws;
    size_t off = 0;
    unsigned short* Gx  = (unsigned short*)(ws + off); off += (size_t)SEQ*BATCH*NG*2;   // 100.7 MB
    unsigned short* xb  = (unsigned short*)(ws + off); off += (size_t)SEQ*BATCH*IN*2;   // 16.8 MB
    unsigned short* WxT = (unsigned short*)(ws + off); off += (size_t)NG*IN*2;
    unsigned short* WhT = (unsigned short*)(ws + off); off += (size_t)NG*HID*2;
    float* biases       = (float*)(ws + off);          off += (size_t)(NG+HID)*4;
    unsigned* htag      = (unsigned*)(ws + off);       off += (size_t)2*BATCH*HID*4;    // 256 KB tagged h
    if (ws_size < off) return;

    hipLaunchKernelGGL(prep_weights, dim3(6), dim3(256), 0, stream,
                       Wr, br, Wu, bu, Wni, bni, Wnh, bnh, WxT, WhT, biases);
    hipLaunchKernelGGL(cvt_x, dim3(8192), dim3(256), 0, stream, x, xb, SEQ*BATCH*IN);
    hipLaunchKernelGGL(gemm_x, dim3(512, 6), dim3(256), 0, stream, xb, WxT, biases, Gx);
    // Zero tagged-h (tag 0 == valid h_0 == zeros).
    hipMemsetAsync(htag, 0, (size_t)2*BATCH*HID*4, stream);

    void* args[] = { &Gx, &WhT, &biases, &htag, &out };
    hipLaunchCooperativeKernel((void*)gru_seq, dim3(128), dim3(256), args, 0, stream);
}

// Round 4
// 3062.522 us; speedup vs baseline: 1.0802x; 1.0802x over previous
//
#include <hip/hip_runtime.h>
#include <hip/hip_bf16.h>

#define SEQ 512
#define BATCH 64
#define IN 256
#define HID 512
#define NG 1536  // 3*HID

typedef short short8 __attribute__((ext_vector_type(8)));
typedef float f32x4 __attribute__((ext_vector_type(4)));

__device__ __forceinline__ unsigned short f2bf(float f) {
    union { float f; unsigned u; } v; v.f = f;
    return (unsigned short)((v.u + 0x7fffu + ((v.u >> 16) & 1u)) >> 16);
}
__device__ __forceinline__ float bf2f(unsigned short h) {
    union { unsigned u; float f; } v; v.u = ((unsigned)h) << 16; return v.f;
}

// Build gate-major bf16 weight blocks + folded bias constants.
__global__ void prep_weights(const float* __restrict__ Wr, const float* __restrict__ br,
                             const float* __restrict__ Wu, const float* __restrict__ bu,
                             const float* __restrict__ Wni, const float* __restrict__ bni,
                             const float* __restrict__ Wnh, const float* __restrict__ bnh,
                             unsigned short* __restrict__ WxT, unsigned short* __restrict__ WhT,
                             float* __restrict__ biases)
{
    int n = blockIdx.x * blockDim.x + threadIdx.x;
    if (n >= NG) return;
    int g = n >> 9, j = n & 511;
    const float* xsrc; const float* hsrc; float bias;
    if (g == 0)      { xsrc = Wr + (size_t)j*770; hsrc = Wr + (size_t)j*770 + 257;
                       bias = Wr[(size_t)j*770+256] + Wr[(size_t)j*770+769] + br[j]; }
    else if (g == 1) { xsrc = Wu + (size_t)j*770; hsrc = Wu + (size_t)j*770 + 257;
                       bias = Wu[(size_t)j*770+256] + Wu[(size_t)j*770+769] + bu[j]; }
    else             { xsrc = Wni + (size_t)j*257; hsrc = Wnh + (size_t)j*513;
                       bias = Wni[(size_t)j*257+256] + bni[j]; }
    for (int i = 0; i < IN; ++i)  WxT[(size_t)n*IN + i]  = f2bf(xsrc[i]);
    for (int k = 0; k < HID; ++k) WhT[(size_t)n*HID + k] = f2bf(hsrc[k]);
    biases[n] = bias;
    if (g == 2) biases[NG + j] = Wnh[(size_t)j*513 + 512] + bnh[j];
}

__global__ void cvt_x(const float* __restrict__ x, unsigned short* __restrict__ xb, int n)
{
    int i = (blockIdx.x * blockDim.x + threadIdx.x) * 4;
    if (i >= n) return;
    float4 v = *reinterpret_cast<const float4*>(x + i);
    ushort4 o;
    o.x = f2bf(v.x); o.y = f2bf(v.y); o.z = f2bf(v.z); o.w = f2bf(v.w);
    *reinterpret_cast<ushort4*>(xb + i) = o;
}

// Gx[m][n] = sum_i xb[m][i]*WxT[n][i] + biases[n],  m = t*64+b, stored bf16.
__global__ __launch_bounds__(256) void gemm_x(const unsigned short* __restrict__ xb,
                                              const unsigned short* __restrict__ WxT,
                                              const float* __restrict__ biases,
                                              unsigned short* __restrict__ Gx)
{
    const int lane = threadIdx.x & 63;
    const int wave = threadIdx.x >> 6;
    const int m0 = blockIdx.x * 64;
    const int n0 = blockIdx.y * 256 + wave * 64;
    const int laneM = lane & 15, laneK8 = (lane >> 4) * 8;
    f32x4 acc[4][4] = {};
#pragma unroll
    for (int k0 = 0; k0 < IN; k0 += 32) {
        short8 A[4], Bf[4];
#pragma unroll
        for (int mi = 0; mi < 4; ++mi)
            A[mi] = *reinterpret_cast<const short8*>(xb + (size_t)(m0 + mi*16 + laneM)*IN + k0 + laneK8);
#pragma unroll
        for (int ni = 0; ni < 4; ++ni)
            Bf[ni] = *reinterpret_cast<const short8*>(WxT + (size_t)(n0 + ni*16 + laneM)*IN + k0 + laneK8);
#pragma unroll
        for (int mi = 0; mi < 4; ++mi)
#pragma unroll
            for (int ni = 0; ni < 4; ++ni)
                acc[mi][ni] = __builtin_amdgcn_mfma_f32_16x16x32_bf16(A[mi], Bf[ni], acc[mi][ni], 0, 0, 0);
    }
    const int crow = (lane >> 4) * 4, ccol = lane & 15;
#pragma unroll
    for (int mi = 0; mi < 4; ++mi)
#pragma unroll
        for (int ni = 0; ni < 4; ++ni) {
            int nn = n0 + ni*16 + ccol;
            float bias = biases[nn];
#pragma unroll
            for (int v = 0; v < 4; ++v) {
                int mm = m0 + mi*16 + crow + v;
                Gx[(size_t)mm * NG + nn] = f2bf(acc[mi][ni][v] + bias);
            }
        }
}

// Persistent recurrent kernel. 128 blocks x 256 threads (cooperative launch).
// 8 independent groups of 8 batch rows. Group g = blocks {i : i%8==g} -> under
// round-robin dispatch all 16 blocks of a group land on XCD g, so the h-exchange
// goes through the XCD-LOCAL (coherent) L2 via volatile (sc0) tagged words.
// Every word is self-validating: u32 = (tag<<16)|bf16, tag = step of the value.
// Producers dual-store (volatile -> local L2, agent-atomic -> memory-side);
// consumers poll the local mirror, falling back to the memory-side copy every
// 4th sweep with per-word freshness merge. Correct under ANY block placement
// (worst case: paced by memory-side RTT); fast when the %8 heuristic holds.
__global__ __launch_bounds__(256, 1) void gru_seq(const unsigned short* __restrict__ Gx,
                                                  const unsigned short* __restrict__ WhT,
                                                  const float* __restrict__ biases,
                                                  unsigned* __restrict__ htagL,
                                                  unsigned* __restrict__ htagG,
                                                  float* __restrict__ out)
{
    const int blk = blockIdx.x;
    const int g = blk & 7, jt = blk >> 3;
    const int b0 = g * 8, j0 = jt * 32;
    const int lane = threadIdx.x & 63;
    const int wave = threadIdx.x >> 6;
    const int laneM = lane & 15, laneK8 = (lane >> 4) * 8;
    __shared__ float red[4][3][2][8][16];

    // Preload recurrent weight fragments once: 3 gates x 2 n-tiles x 4 k-frags.
    short8 Bf[3][2][4];
#pragma unroll
    for (int gg = 0; gg < 3; ++gg)
#pragma unroll
        for (int nt = 0; nt < 2; ++nt)
#pragma unroll
            for (int kk = 0; kk < 4; ++kk) {
                int n = gg * HID + j0 + nt * 16 + laneM;
                int k = wave * 128 + kk * 32 + laneK8;
                Bf[gg][nt][kk] = *reinterpret_cast<const short8*>(WhT + (size_t)n * HID + k);
            }

    const int row = threadIdx.x >> 5, col = threadIdx.x & 31;   // 8 x 32 epilogue map
    const int b = b0 + row, jj = j0 + col;
    const float cnh = biases[NG + jj];
    float h_old = 0.f;
    const size_t gx0 = (size_t)b * NG + jj;
    unsigned short pr = Gx[gx0], pu = Gx[gx0 + HID], pn = Gx[gx0 + 2*HID];

    // Per-thread poll base: batch row b0 + (laneM&7) (rows 8-15 mirror 0-7),
    // k-slice = wave*128 + laneK8, 4 frags at +0/+32/+64/+96.
    const size_t kbase = (size_t)(b0 + (laneM & 7)) * HID + wave * 128 + laneK8;

    for (int t = 0; t < SEQ; ++t) {
        // Prefetch next step's x-projections (independent, overlaps the poll).
        unsigned short nr = 0, nu = 0, nn2 = 0;
        if (t + 1 < SEQ) {
            size_t gi = gx0 + (size_t)(t + 1) * BATCH * NG;
            nr = Gx[gi]; nu = Gx[gi + HID]; nn2 = Gx[gi + 2*HID];
        }

        // Poll tagged h_t words (32 per thread) until all fresh (tag == t).
        const unsigned need = (unsigned)t << 16;
        const size_t pbase = (size_t)(t & 1) * BATCH * HID + kbase;
        const unsigned* gp = htagG + pbase;
        const volatile unsigned* lp = (const volatile unsigned*)htagL + pbase;
        unsigned cur[32];
#pragma unroll
        for (int w = 0; w < 32; ++w) cur[w] = ~need;  // guaranteed stale
        int sweep = 0;
        for (;;) {
            unsigned nw[32];
            if ((sweep & 3) == 3) {
#pragma unroll
                for (int f = 0; f < 4; ++f)
#pragma unroll
                    for (int w = 0; w < 8; ++w)
                        nw[f*8+w] = __hip_atomic_load(gp + f*32 + w, __ATOMIC_RELAXED, __HIP_MEMORY_SCOPE_AGENT);
            } else {
#pragma unroll
                for (int f = 0; f < 4; ++f)
#pragma unroll
                    for (int w = 0; w < 8; ++w)
                        nw[f*8+w] = lp[f*32 + w];
            }
            unsigned bad = 0;
#pragma unroll
            for (int w = 0; w < 32; ++w) {
                cur[w] = ((cur[w] ^ need) & 0xffff0000u) ? nw[w] : cur[w];
                bad |= (cur[w] ^ need) & 0xffff0000u;
            }
            ++sweep;
            if (__all(bad == 0)) break;
        }

        // Pack bf16 payloads into MFMA A fragments.
        short8 A[4];
#pragma unroll
        for (int kk = 0; kk < 4; ++kk) {
            union { unsigned p[4]; short8 s; } pk;
#pragma unroll
            for (int i = 0; i < 4; ++i)
                pk.p[i] = (cur[kk*8 + 2*i] & 0xffffu) | (cur[kk*8 + 2*i + 1] << 16);
            A[kk] = pk.s;
        }

        f32x4 acc[3][2] = {};
#pragma unroll
        for (int kk = 0; kk < 4; ++kk)
#pragma unroll
            for (int gg = 0; gg < 3; ++gg)
#pragma unroll
                for (int nt = 0; nt < 2; ++nt)
                    acc[gg][nt] = __builtin_amdgcn_mfma_f32_16x16x32_bf16(A[kk], Bf[gg][nt][kk], acc[gg][nt], 0, 0, 0);

        const int crow = (lane >> 4) * 4;
        if (crow < 8) {
#pragma unroll
            for (int v = 0; v < 4; ++v)
#pragma unroll
                for (int gg = 0; gg < 3; ++gg)
#pragma unroll
                    for (int nt = 0; nt < 2; ++nt)
                        red[wave][gg][nt][crow + v][laneM] = acc[gg][nt][v];
        }
        __syncthreads();
        const int nt = col >> 4, c16 = col & 15;
        float rp = red[0][0][nt][row][c16] + red[1][0][nt][row][c16] + red[2][0][nt][row][c16] + red[3][0][nt][row][c16];
        float up = red[0][1][nt][row][c16] + red[1][1][nt][row][c16] + red[2][1][nt][row][c16] + red[3][1][nt][row][c16];
        float np = red[0][2][nt][row][c16] + red[1][2][nt][row][c16] + red[2][2][nt][row][c16] + red[3][2][nt][row][c16];
        float r = 1.f / (1.f + __expf(-(bf2f(pr) + rp)));
        float z = 1.f / (1.f + __expf(-(bf2f(pu) + up)));
        float e = __expf(2.f * (bf2f(pn) + r * (np + cnh)));
        float n = 1.f - 2.f / (e + 1.f);
        float hnew = (1.f - z) * n + z * h_old;
        h_old = hnew;

        // Publish tagged h_{t+1}: volatile -> local L2 mirror, atomic -> memory-side.
        unsigned word = ((unsigned)(t + 1) << 16) | (unsigned)f2bf(hnew);
        size_t pidx = (size_t)((t + 1) & 1) * BATCH * HID + (size_t)b * HID + jj;
        ((volatile unsigned*)htagL)[pidx] = word;
        __hip_atomic_store(htagG + pidx, word, __ATOMIC_RELAXED, __HIP_MEMORY_SCOPE_AGENT);

        out[(size_t)t * BATCH * HID + (size_t)b * HID + jj] = hnew;
        if (t == SEQ - 1) out[(size_t)SEQ * BATCH * HID + (size_t)b * HID + jj] = hnew;
        pr = nr; pu = nu; pn = nn2;

        __syncthreads();  // WAR protection for red[] before next iteration
    }
}

extern "C" void kernel_launch(void* const* d_in, const int* in_sizes, int n_in,
                              void* d_out, int out_size, void* d_ws, size_t ws_size,
                              hipStream_t stream)
{
    const float* x   = (const float*)d_in[0];
    const float* Wr  = (const float*)d_in[1];
    const float* br  = (const float*)d_in[2];
    const float* Wu  = (const float*)d_in[3];
    const float* bu  = (const float*)d_in[4];
    const float* Wni = (const float*)d_in[5];
    const float* bni = (const float*)d_in[6];
    const float* Wnh = (const float*)d_in[7];
    const float* bnh = (const float*)d_in[8];
    float* out = (float*)d_out;

    char* ws = (char*)d_ws;
    size_t off = 0;
    unsigned short* Gx  = (unsigned short*)(ws + off); off += (size_t)SEQ*BATCH*NG*2;   // 100.7 MB
    unsigned short* xb  = (unsigned short*)(ws + off); off += (size_t)SEQ*BATCH*IN*2;   // 16.8 MB
    unsigned short* WxT = (unsigned short*)(ws + off); off += (size_t)NG*IN*2;
    unsigned short* WhT = (unsigned short*)(ws + off); off += (size_t)NG*HID*2;
    float* biases       = (float*)(ws + off);          off += (size_t)(NG+HID)*4;
    unsigned* htagL     = (unsigned*)(ws + off);       off += (size_t)2*BATCH*HID*4;    // 256 KB local mirror
    unsigned* htagG     = (unsigned*)(ws + off);       off += (size_t)2*BATCH*HID*4;    // 256 KB memory-side
    if (ws_size < off) return;

    hipLaunchKernelGGL(prep_weights, dim3(6), dim3(256), 0, stream,
                       Wr, br, Wu, bu, Wni, bni, Wnh, bnh, WxT, WhT, biases);
    hipLaunchKernelGGL(cvt_x, dim3(8192), dim3(256), 0, stream, x, xb, SEQ*BATCH*IN);
    hipLaunchKernelGGL(gemm_x, dim3(512, 6), dim3(256), 0, stream, xb, WxT, biases, Gx);
    // Zero both tagged-h buffers (tag 0 == valid h_0 == zeros); they are contiguous.
    hipMemsetAsync(htagL, 0, (size_t)2 * 2*BATCH*HID*4, stream);

    void* args[] = { &Gx, &WhT, &biases, &htagL, &htagG, &out };
    hipLaunchCooperativeKernel((void*)gru_seq, dim3(128), dim3(256), args, 0, stream);
}